// Round 11
// baseline (453.018 us; speedup 1.0000x reference)
//
#include <hip/hip_runtime.h>
#include <cstdint>
#include <cstddef>

#define NNODES 100000
#define DIM 128
#define WLD 136   // LDS stride (u16) for W planes

typedef unsigned short u16;
typedef uint32_t u32;
typedef __attribute__((ext_vector_type(8))) short v8s;
typedef __attribute__((ext_vector_type(4))) float v4f;

__device__ __forceinline__ float bf2f(u32 u) {
  union { u32 i; float f; } x; x.i = u << 16; return x.f;
}
__device__ __forceinline__ u16 f2bf(float f) {
  union { float f; u32 i; } x; x.f = f;
  u32 r = x.i + 0x7fffu + ((x.i >> 16) & 1u);  // RNE
  return (u16)(r >> 16);
}
// pack f32 -> (hi bf16) | (lo-residual bf16 << 16)
__device__ __forceinline__ u32 packsplit(float f) {
  u16 h = f2bf(f);
  float r = f - bf2f(h);
  u16 l = f2bf(r);
  return (u32)h | ((u32)l << 16);
}
__device__ __forceinline__ float unpacksum(u32 p) {
  return bf2f(p & 0xffffu) + bf2f(p >> 16);
}

// swizzled packed-plane index: wave-store of one (rg,ct) slab = 256 contiguous bytes
__device__ __forceinline__ size_t pidx(int row, int col) {
  return ((size_t)(row >> 4) << 11) +
         (size_t)(((((row & 3) << 3) + (col >> 4)) << 6) +
                  (((row >> 2) & 3) << 4) + (col & 15));
}

// =================== unified CSR build (3 lists concatenated) ===================

__global__ void count_all(const int* __restrict__ d2u, const int* __restrict__ sle,
                          const int* __restrict__ u2d, int E1, int E2, int E3,
                          int* __restrict__ cnt) {
  int e = blockIdx.x * 256 + threadIdx.x;
  int idx;
  if (e < E1)            idx = d2u[E1 + e];
  else if (e < E1 + E2)  idx = NNODES + sle[E2 + (e - E1)];
  else if (e < E1 + E2 + E3) idx = 2 * NNODES + u2d[E3 + (e - E1 - E2)];
  else return;
  atomicAdd(&cnt[idx], 1);
}

__global__ void fill_all(const int* __restrict__ d2u, const int* __restrict__ sle,
                         const int* __restrict__ u2d, int E1, int E2, int E3,
                         const int* __restrict__ rs, int* __restrict__ fill,
                         int* __restrict__ eidx) {
  int e = blockIdx.x * 256 + threadIdx.x;
  int idx, src;
  if (e < E1)            { idx = d2u[E1 + e];                src = d2u[e]; }
  else if (e < E1 + E2)  { int q = e - E1; idx = NNODES + sle[E2 + q];     src = sle[q]; }
  else if (e < E1 + E2 + E3) { int q = e - E1 - E2; idx = 2 * NNODES + u2d[E3 + q]; src = u2d[q]; }
  else return;
  int p = rs[idx] + atomicAdd(&fill[idx], 1);
  eidx[p] = src;
}

__global__ void scan_blocks(const int* __restrict__ in, int* __restrict__ out,
                            int* __restrict__ bsum, int n) {
  __shared__ int wsum[4];
  const int tid = threadIdx.x;
  const int base = blockIdx.x * 1024 + tid * 4;
  int v0 = 0, v1 = 0, v2 = 0, v3 = 0;
  if (base + 0 < n) v0 = in[base + 0];
  if (base + 1 < n) v1 = in[base + 1];
  if (base + 2 < n) v2 = in[base + 2];
  if (base + 3 < n) v3 = in[base + 3];
  const int tsum = v0 + v1 + v2 + v3;
  const int lane = tid & 63, wid = tid >> 6;
  int x = tsum;
  for (int off = 1; off < 64; off <<= 1) {
    int y = __shfl_up(x, off, 64);
    if (lane >= off) x += y;
  }
  if (lane == 63) wsum[wid] = x;
  __syncthreads();
  int woff = 0;
  for (int w = 0; w < wid; ++w) woff += wsum[w];
  const int excl = woff + x - tsum;
  if (base + 0 < n) out[base + 0] = excl;
  if (base + 1 < n) out[base + 1] = excl + v0;
  if (base + 2 < n) out[base + 2] = excl + v0 + v1;
  if (base + 3 < n) out[base + 3] = excl + v0 + v1 + v2;
  if (tid == 255) bsum[blockIdx.x] = woff + x;
}

__global__ void scan_top(int* __restrict__ bsum, int nb) {
  __shared__ int tmp[1024];
  const int tid = threadIdx.x;
  for (int i = tid; i < 1024; i += 256) tmp[i] = (i < nb) ? bsum[i] : 0;
  __syncthreads();
  for (int off = 1; off < 1024; off <<= 1) {
    int vals[4];
#pragma unroll
    for (int j = 0; j < 4; ++j) { int i = tid + j * 256; vals[j] = (i >= off) ? tmp[i - off] : 0; }
    __syncthreads();
#pragma unroll
    for (int j = 0; j < 4; ++j) { int i = tid + j * 256; tmp[i] += vals[j]; }
    __syncthreads();
  }
  for (int i = tid; i < nb; i += 256) {
    int orig = bsum[i];
    bsum[i] = tmp[i] - orig;   // exclusive
  }
}

__global__ void scan_add(int* __restrict__ out, const int* __restrict__ bsum, int n) {
  const int b = blockIdx.x;
  const int off = bsum[b];
  const int base = b * 1024 + threadIdx.x * 4;
#pragma unroll
  for (int j = 0; j < 4; ++j)
    if (base + j < n) out[base + j] += off;
}

__global__ void make_rnorm(const int* __restrict__ cntB, float* __restrict__ rnorm, int n) {
  int i = blockIdx.x * 256 + threadIdx.x;
  if (i < n) rnorm[i] = rsqrtf((float)cntB[i] + 1.0f);
}

__global__ void make_w_planes(const float* __restrict__ W0, const float* __restrict__ W1,
                              const float* __restrict__ W2,
                              u16* __restrict__ Whi, u16* __restrict__ Wlo) {
  int i = blockIdx.x * 256 + threadIdx.x;
  if (i >= 3 * DIM * DIM) return;
  int m = i / (DIM * DIM);
  int idx = i - m * DIM * DIM;
  int k = idx >> 7, c = idx & 127;
  const float* W = (m == 0) ? W0 : ((m == 1) ? W1 : W2);
  u32 p = packsplit(W[idx]);
  int o = m * DIM * DIM + c * DIM + k;
  Whi[o] = (u16)(p & 0xffffu);
  Wlo[o] = (u16)(p >> 16);
}

// =================== gathers (32 threads / node, 4 cols each) ===================

// agg[i] = mean of x[src] rows; write packed swizzled plane (GEMM A-operand)
__global__ void gather_mean_pack(const float* __restrict__ x, const int* __restrict__ rs,
                                 const int* __restrict__ cnt, const int* __restrict__ eidx,
                                 u32* __restrict__ opk, int n) {
  int gid = blockIdx.x * 256 + threadIdx.x;
  int i = gid >> 5;
  if (i >= n) return;
  int c = (gid & 31) << 2;
  int start = rs[i], m = cnt[i];
  float4 acc = {0.f, 0.f, 0.f, 0.f};
  int j = 0;
  for (; j + 1 < m; j += 2) {
    int s0 = eidx[start + j], s1 = eidx[start + j + 1];
    float4 v0 = *(const float4*)(x + (size_t)s0 * DIM + c);
    float4 v1 = *(const float4*)(x + (size_t)s1 * DIM + c);
    acc.x += v0.x + v1.x; acc.y += v0.y + v1.y;
    acc.z += v0.z + v1.z; acc.w += v0.w + v1.w;
  }
  if (j < m) {
    int s = eidx[start + j];
    float4 v = *(const float4*)(x + (size_t)s * DIM + c);
    acc.x += v.x; acc.y += v.y; acc.z += v.z; acc.w += v.w;
  }
  float inv = 1.0f / fmaxf((float)m, 1.0f);
  uint4 pk;
  pk.x = packsplit(acc.x * inv);
  pk.y = packsplit(acc.y * inv);
  pk.z = packsplit(acc.z * inv);
  pk.w = packsplit(acc.w * inv);
  *(uint4*)(opk + pidx(i, c)) = pk;
}

// x2[i] = rnorm[i]*sum_e rnorm[s]*h[s] + h[i]*rnorm[i]^2 + bias ; h = packed plane
__global__ void gather_gcn(const u32* __restrict__ hpk,
                           const int* __restrict__ rs, const int* __restrict__ cnt,
                           const int* __restrict__ eidx, const float* __restrict__ rnorm,
                           const float* __restrict__ bias, float* __restrict__ out, int n) {
  int gid = blockIdx.x * 256 + threadIdx.x;
  int i = gid >> 5;
  if (i >= n) return;
  int c = (gid & 31) << 2;
  int start = rs[i], m = cnt[i];
  float4 acc = {0.f, 0.f, 0.f, 0.f};
  int j = 0;
  for (; j + 1 < m; j += 2) {
    int s0 = eidx[start + j], s1 = eidx[start + j + 1];
    float r0 = rnorm[s0], r1 = rnorm[s1];
    uint4 p0 = *(const uint4*)(hpk + pidx(s0, c));
    uint4 p1 = *(const uint4*)(hpk + pidx(s1, c));
    acc.x = fmaf(r0, unpacksum(p0.x), fmaf(r1, unpacksum(p1.x), acc.x));
    acc.y = fmaf(r0, unpacksum(p0.y), fmaf(r1, unpacksum(p1.y), acc.y));
    acc.z = fmaf(r0, unpacksum(p0.z), fmaf(r1, unpacksum(p1.z), acc.z));
    acc.w = fmaf(r0, unpacksum(p0.w), fmaf(r1, unpacksum(p1.w), acc.w));
  }
  if (j < m) {
    int s = eidx[start + j];
    float rn = rnorm[s];
    uint4 pv = *(const uint4*)(hpk + pidx(s, c));
    acc.x = fmaf(rn, unpacksum(pv.x), acc.x);
    acc.y = fmaf(rn, unpacksum(pv.y), acc.y);
    acc.z = fmaf(rn, unpacksum(pv.z), acc.z);
    acc.w = fmaf(rn, unpacksum(pv.w), acc.w);
  }
  float ri = rnorm[i];
  float invd = ri * ri;
  uint4 ps = *(const uint4*)(hpk + pidx(i, c));
  float4 bv = *(const float4*)(bias + c);
  float4 o;
  o.x = fmaf(ri, acc.x, fmaf(invd, unpacksum(ps.x), bv.x));
  o.y = fmaf(ri, acc.y, fmaf(invd, unpacksum(ps.y), bv.y));
  o.z = fmaf(ri, acc.z, fmaf(invd, unpacksum(ps.z), bv.z));
  o.w = fmaf(ri, acc.w, fmaf(invd, unpacksum(ps.w), bv.w));
  *(float4*)(out + (size_t)i * DIM + c) = o;
}

// =================== MFMA split-bf16 GEMM, packed swizzled A, LDS-staged W ===================
// A is a packed u32 plane (hi|lo<<16) in pidx layout: lane A-load = 2x 16B
// contiguous; OSPLIT epilogue wave-store of one (rg,ct) slab = 256 contiguous
// bytes (full lines -> kills the r10 RMW inflation: WRITE 80->51 MB predicted).
// acc += ah*wh + ah*wl + al*wh (al*wl ~2^-18 dropped). 8-wave blocks (r10 MLP).
// Fragment maps (m89/m91): A: m=lane&15,k=quad*8+j ; B: n=lane&15,k=quad*8+j ;
// D: row=quad*4+reg, col=lane&15. In-place A->out safe (wave owns its 16 rows).
template<int PRE, int BIAS, int RELU, int OSPLIT>
__global__ __launch_bounds__(512) void gemm_mfma(
    const u32* __restrict__ Apk,
    const u16* __restrict__ Wgh, const u16* __restrict__ Wgl,
    const float* __restrict__ bias, const float* pre,
    float* outf, u32* opk, int nrows)
{
  __shared__ u16 Wh[DIM * WLD];   // 34.8 KB
  __shared__ u16 Wl[DIM * WLD];   // 34.8 KB
  const int tid = threadIdx.x;
  const int wave = tid >> 6, lane = tid & 63;
  const int lr = lane & 15, quad = lane >> 4;
  const int rowbase = blockIdx.x * 128 + wave * 16;   // 8 waves x 16 rows

  // A loads (issue before staging; 2x uint4 per kk, contiguous 32 B)
  int arow = rowbase + lr;
  if (arow >= nrows) arow = nrows - 1;
  uint4 pa[4][2];
#pragma unroll
  for (int kk = 0; kk < 4; ++kk) {
    size_t o = pidx(arow, kk * 32 + quad * 8);
    pa[kk][0] = *(const uint4*)(Apk + o);
    pa[kk][1] = *(const uint4*)(Apk + o + 4);
  }

  // stage W planes
  for (int i = tid; i < DIM * DIM / 8; i += 512) {
    int cc = i >> 4, k8 = (i & 15) << 3;
    *(uint4*)&Wh[cc * WLD + k8] = ((const uint4*)Wgh)[i];
    *(uint4*)&Wl[cc * WLD + k8] = ((const uint4*)Wgl)[i];
  }
  __syncthreads();

  // unpack packed u32 -> hi/lo bf16 fragments
  v8s afh[4], afl[4];
#pragma unroll
  for (int kk = 0; kk < 4; ++kk) {
    u32 u[8] = {pa[kk][0].x, pa[kk][0].y, pa[kk][0].z, pa[kk][0].w,
                pa[kk][1].x, pa[kk][1].y, pa[kk][1].z, pa[kk][1].w};
#pragma unroll
    for (int j = 0; j < 8; ++j) {
      afh[kk][j] = (short)(u[j] & 0xffffu);
      afl[kk][j] = (short)(u[j] >> 16);
    }
  }

  v4f acc[8];
#pragma unroll
  for (int ct = 0; ct < 8; ++ct) acc[ct] = (v4f){0.f, 0.f, 0.f, 0.f};

#pragma unroll
  for (int kk = 0; kk < 4; ++kk) {
#pragma unroll
    for (int ct = 0; ct < 8; ++ct) {
      const int wo = (ct * 16 + lr) * WLD + kk * 32 + quad * 8;
      v8s bh = *(const v8s*)&Wh[wo];
      v8s bl = *(const v8s*)&Wl[wo];
      acc[ct] = __builtin_amdgcn_mfma_f32_16x16x32_bf16(afh[kk], bh, acc[ct], 0, 0, 0);
      acc[ct] = __builtin_amdgcn_mfma_f32_16x16x32_bf16(afh[kk], bl, acc[ct], 0, 0, 0);
      acc[ct] = __builtin_amdgcn_mfma_f32_16x16x32_bf16(afl[kk], bh, acc[ct], 0, 0, 0);
    }
  }

  if (OSPLIT) {
    // packed swizzled store: lanebase + (rg*8+ct)*64 is 256B-contiguous per inst
    const size_t lanebase = ((size_t)(rowbase >> 4) << 11) + quad * 16 + lr;
#pragma unroll
    for (int rg = 0; rg < 4; ++rg) {
      int r = rowbase + quad * 4 + rg;
      if (r < nrows) {
#pragma unroll
        for (int ct = 0; ct < 8; ++ct) {
          const int col = ct * 16 + lr;
          float v = acc[ct][rg] + (BIAS ? bias[col] : 0.f);
          if (PRE) v += pre[(size_t)r * DIM + col];
          if (RELU) v = fmaxf(v, 0.f);
          opk[lanebase + (size_t)((rg << 3) + ct) * 64] = packsplit(v);
        }
      }
    }
  } else {
#pragma unroll
    for (int ct = 0; ct < 8; ++ct) {
      const int col = ct * 16 + lr;
      float bv = BIAS ? bias[col] : 0.f;
#pragma unroll
      for (int rg = 0; rg < 4; ++rg) {
        int r = rowbase + quad * 4 + rg;
        if (r < nrows) {
          size_t off = (size_t)r * DIM + col;
          float v = acc[ct][rg] + bv;
          if (PRE) v += pre[off];
          if (RELU) v = fmaxf(v, 0.f);
          outf[off] = v;
        }
      }
    }
  }
}

// =================== host ===================

extern "C" void kernel_launch(void* const* d_in, const int* in_sizes, int n_in,
                              void* d_out, int out_size, void* d_ws, size_t ws_size,
                              hipStream_t stream) {
  const float* emb = (const float*)d_in[0];
  const float* Wd  = (const float*)d_in[1];
  const float* bd  = (const float*)d_in[2];
  const float* Wg  = (const float*)d_in[3];
  const float* bg  = (const float*)d_in[4];
  const float* Wu  = (const float*)d_in[5];
  const float* bu  = (const float*)d_in[6];
  const int* d2u = (const int*)d_in[7];
  const int* sle = (const int*)d_in[8];
  const int* u2d = (const int*)d_in[9];
  const int E1 = in_sizes[7] / 2;   // 100000
  const int E2 = in_sizes[8] / 2;   // 600000
  const int E3 = in_sizes[9] / 2;   // 100000
  const int Etot = E1 + E2 + E3;
  const int N  = NNODES;
  const size_t nd = (size_t)N * DIM;

  u32* Apk  = (u32*)d_ws;          // packed swizzled plane [nd u32] (51.2 MB)
  int* cnt  = (int*)(Apk + nd);    // [3N]
  int* fill = cnt + 3 * N;         // [3N]
  int* rs   = fill + 3 * N;        // [3N]
  int* eidx = rs + 3 * N;          // [Etot]
  float* rnorm = (float*)(eidx + Etot);
  int* bsum = (int*)(rnorm + N);
  u16* Whi = (u16*)(bsum + 1024);
  u16* Wlo = Whi + 3 * DIM * DIM;
  float* bufB = (float*)d_out;

  const int gemm_blocks = (N + 127) / 128;        // 782
  const int nscan = (3 * N + 1023) / 1024;        // 293
  const int ngather = (N * 32 + 255) / 256;       // 12500

  // ---- prep: W planes + unified CSR ----
  (void)hipMemsetAsync(cnt, 0, (size_t)6 * N * sizeof(int), stream);
  make_w_planes<<<(3 * DIM * DIM + 255) / 256, 256, 0, stream>>>(Wd, Wg, Wu, Whi, Wlo);
  count_all<<<(Etot + 255) / 256, 256, 0, stream>>>(d2u, sle, u2d, E1, E2, E3, cnt);
  make_rnorm<<<(N + 255) / 256, 256, 0, stream>>>(cnt + N, rnorm, N);
  scan_blocks<<<nscan, 256, 0, stream>>>(cnt, rs, bsum, 3 * N);
  scan_top<<<1, 256, 0, stream>>>(bsum, nscan);
  scan_add<<<nscan, 256, 0, stream>>>(rs, bsum, 3 * N);
  fill_all<<<(Etot + 255) / 256, 256, 0, stream>>>(d2u, sle, u2d, E1, E2, E3, rs, fill, eidx);

  // ---- stage A: agg1 = mean(emb) -> packed ; x1 = relu(emb + agg1@Wd + bd) -> packed (in-place) ----
  gather_mean_pack<<<ngather, 256, 0, stream>>>(emb, rs, cnt, eidx, Apk, N);
  gemm_mfma<1, 1, 1, 1><<<gemm_blocks, 512, 0, stream>>>(Apk, Whi, Wlo, bd, emb,
                                                         nullptr, Apk, N);

  // ---- stage B: h = x1@Wg -> packed (in-place) ; x2 = gcn(h) -> d_out ----
  gemm_mfma<0, 0, 0, 1><<<gemm_blocks, 512, 0, stream>>>(Apk, Whi + DIM * DIM,
                                                         Wlo + DIM * DIM, nullptr, nullptr,
                                                         nullptr, Apk, N);
  gather_gcn<<<ngather, 256, 0, stream>>>(Apk, rs + N, cnt + N, eidx, rnorm, bg, bufB, N);

  // ---- stage C: agg2 = mean(x2) -> packed ; out = relu(x2 + agg2@Wu + bu) -> f32 d_out ----
  gather_mean_pack<<<ngather, 256, 0, stream>>>(bufB, rs + 2 * N, cnt + 2 * N, eidx, Apk, N);
  gemm_mfma<1, 1, 1, 0><<<gemm_blocks, 512, 0, stream>>>(Apk, Whi + 2 * DIM * DIM,
                                                         Wlo + 2 * DIM * DIM, bu, bufB,
                                                         bufB, nullptr, N);
}

// Round 12
// 441.734 us; speedup vs baseline: 1.0255x; 1.0255x over previous
//
#include <hip/hip_runtime.h>
#include <cstdint>
#include <cstddef>

#define NNODES 100000
#define DIM 128
#define WLD 136   // LDS stride (u16) for W planes

typedef unsigned short u16;
typedef uint32_t u32;
typedef __attribute__((ext_vector_type(8))) short v8s;
typedef __attribute__((ext_vector_type(4))) float v4f;

__device__ __forceinline__ float bf2f(u32 u) {
  union { u32 i; float f; } x; x.i = u << 16; return x.f;
}
__device__ __forceinline__ u16 f2bf(float f) {
  union { float f; u32 i; } x; x.f = f;
  u32 r = x.i + 0x7fffu + ((x.i >> 16) & 1u);  // RNE
  return (u16)(r >> 16);
}
// pack f32 -> (hi bf16) | (lo-residual bf16 << 16)
__device__ __forceinline__ u32 packsplit(float f) {
  u16 h = f2bf(f);
  float r = f - bf2f(h);
  u16 l = f2bf(r);
  return (u32)h | ((u32)l << 16);
}
__device__ __forceinline__ float unpacksum(u32 p) {
  return bf2f(p & 0xffffu) + bf2f(p >> 16);
}

// swizzled packed-plane index: wave-store of one (rg,ct) slab = 256 contiguous bytes
__device__ __forceinline__ size_t pidx(int row, int col) {
  return ((size_t)(row >> 4) << 11) +
         (size_t)(((((row & 3) << 3) + (col >> 4)) << 6) +
                  (((row >> 2) & 3) << 4) + (col & 15));
}

// =================== unified CSR build (3 lists concatenated) ===================

__global__ void count_all(const int* __restrict__ d2u, const int* __restrict__ sle,
                          const int* __restrict__ u2d, int E1, int E2, int E3,
                          int* __restrict__ cnt) {
  int e = blockIdx.x * 256 + threadIdx.x;
  int idx;
  if (e < E1)            idx = d2u[E1 + e];
  else if (e < E1 + E2)  idx = NNODES + sle[E2 + (e - E1)];
  else if (e < E1 + E2 + E3) idx = 2 * NNODES + u2d[E3 + (e - E1 - E2)];
  else return;
  atomicAdd(&cnt[idx], 1);
}

__global__ void fill_all(const int* __restrict__ d2u, const int* __restrict__ sle,
                         const int* __restrict__ u2d, int E1, int E2, int E3,
                         const int* __restrict__ rs, int* __restrict__ fill,
                         int* __restrict__ eidx) {
  int e = blockIdx.x * 256 + threadIdx.x;
  int idx, src;
  if (e < E1)            { idx = d2u[E1 + e];                src = d2u[e]; }
  else if (e < E1 + E2)  { int q = e - E1; idx = NNODES + sle[E2 + q];     src = sle[q]; }
  else if (e < E1 + E2 + E3) { int q = e - E1 - E2; idx = 2 * NNODES + u2d[E3 + q]; src = u2d[q]; }
  else return;
  int p = rs[idx] + atomicAdd(&fill[idx], 1);
  eidx[p] = src;
}

__global__ void scan_blocks(const int* __restrict__ in, int* __restrict__ out,
                            int* __restrict__ bsum, int n) {
  __shared__ int wsum[4];
  const int tid = threadIdx.x;
  const int base = blockIdx.x * 1024 + tid * 4;
  int v0 = 0, v1 = 0, v2 = 0, v3 = 0;
  if (base + 0 < n) v0 = in[base + 0];
  if (base + 1 < n) v1 = in[base + 1];
  if (base + 2 < n) v2 = in[base + 2];
  if (base + 3 < n) v3 = in[base + 3];
  const int tsum = v0 + v1 + v2 + v3;
  const int lane = tid & 63, wid = tid >> 6;
  int x = tsum;
  for (int off = 1; off < 64; off <<= 1) {
    int y = __shfl_up(x, off, 64);
    if (lane >= off) x += y;
  }
  if (lane == 63) wsum[wid] = x;
  __syncthreads();
  int woff = 0;
  for (int w = 0; w < wid; ++w) woff += wsum[w];
  const int excl = woff + x - tsum;
  if (base + 0 < n) out[base + 0] = excl;
  if (base + 1 < n) out[base + 1] = excl + v0;
  if (base + 2 < n) out[base + 2] = excl + v0 + v1;
  if (base + 3 < n) out[base + 3] = excl + v0 + v1 + v2;
  if (tid == 255) bsum[blockIdx.x] = woff + x;
}

__global__ void scan_top(int* __restrict__ bsum, int nb) {
  __shared__ int tmp[1024];
  const int tid = threadIdx.x;
  for (int i = tid; i < 1024; i += 256) tmp[i] = (i < nb) ? bsum[i] : 0;
  __syncthreads();
  for (int off = 1; off < 1024; off <<= 1) {
    int vals[4];
#pragma unroll
    for (int j = 0; j < 4; ++j) { int i = tid + j * 256; vals[j] = (i >= off) ? tmp[i - off] : 0; }
    __syncthreads();
#pragma unroll
    for (int j = 0; j < 4; ++j) { int i = tid + j * 256; tmp[i] += vals[j]; }
    __syncthreads();
  }
  for (int i = tid; i < nb; i += 256) {
    int orig = bsum[i];
    bsum[i] = tmp[i] - orig;   // exclusive
  }
}

__global__ void scan_add(int* __restrict__ out, const int* __restrict__ bsum, int n) {
  const int b = blockIdx.x;
  const int off = bsum[b];
  const int base = b * 1024 + threadIdx.x * 4;
#pragma unroll
  for (int j = 0; j < 4; ++j)
    if (base + j < n) out[base + j] += off;
}

__global__ void make_rnorm(const int* __restrict__ cntB, float* __restrict__ rnorm, int n) {
  int i = blockIdx.x * 256 + threadIdx.x;
  if (i < n) rnorm[i] = rsqrtf((float)cntB[i] + 1.0f);
}

__global__ void make_w_planes(const float* __restrict__ W0, const float* __restrict__ W1,
                              const float* __restrict__ W2,
                              u16* __restrict__ Whi, u16* __restrict__ Wlo) {
  int i = blockIdx.x * 256 + threadIdx.x;
  if (i >= 3 * DIM * DIM) return;
  int m = i / (DIM * DIM);
  int idx = i - m * DIM * DIM;
  int k = idx >> 7, c = idx & 127;
  const float* W = (m == 0) ? W0 : ((m == 1) ? W1 : W2);
  u32 p = packsplit(W[idx]);
  int o = m * DIM * DIM + c * DIM + k;
  Whi[o] = (u16)(p & 0xffffu);
  Wlo[o] = (u16)(p >> 16);
}

// =================== gathers ===================

// agg[i] = mean of x[src] rows; write packed swizzled plane (32 t/node)
__global__ void gather_mean_pack(const float* __restrict__ x, const int* __restrict__ rs,
                                 const int* __restrict__ cnt, const int* __restrict__ eidx,
                                 u32* __restrict__ opk, int n) {
  int gid = blockIdx.x * 256 + threadIdx.x;
  int i = gid >> 5;
  if (i >= n) return;
  int c = (gid & 31) << 2;
  int start = rs[i], m = cnt[i];
  float4 acc = {0.f, 0.f, 0.f, 0.f};
  int j = 0;
  for (; j + 1 < m; j += 2) {
    int s0 = eidx[start + j], s1 = eidx[start + j + 1];
    float4 v0 = *(const float4*)(x + (size_t)s0 * DIM + c);
    float4 v1 = *(const float4*)(x + (size_t)s1 * DIM + c);
    acc.x += v0.x + v1.x; acc.y += v0.y + v1.y;
    acc.z += v0.z + v1.z; acc.w += v0.w + v1.w;
  }
  if (j < m) {
    int s = eidx[start + j];
    float4 v = *(const float4*)(x + (size_t)s * DIM + c);
    acc.x += v.x; acc.y += v.y; acc.z += v.z; acc.w += v.w;
  }
  float inv = 1.0f / fmaxf((float)m, 1.0f);
  uint4 pk;
  pk.x = packsplit(acc.x * inv);
  pk.y = packsplit(acc.y * inv);
  pk.z = packsplit(acc.z * inv);
  pk.w = packsplit(acc.w * inv);
  *(uint4*)(opk + pidx(i, c)) = pk;
}

// x2[i] = ri*(sum_e g[s] + g[i]) + bg, where g = rnorm.*h (pre-scaled in GEMM-B).
// 64 threads/node: half-wave j0 = lane>>5 strides edges by 2 (2-way edge-parallel),
// unroll-2 inside (4 row-loads in flight/node); reduce via shfl_xor(32).
__global__ void gather_gcn(const u32* __restrict__ gpk,
                           const int* __restrict__ rs, const int* __restrict__ cnt,
                           const int* __restrict__ eidx, const float* __restrict__ rnorm,
                           const float* __restrict__ bias, float* __restrict__ out, int n) {
  int gid = blockIdx.x * 256 + threadIdx.x;
  int i = gid >> 6;
  if (i >= n) return;
  int sub = gid & 63;
  int c = (sub & 31) << 2;
  int start = rs[i], m = cnt[i];
  float4 acc = {0.f, 0.f, 0.f, 0.f};
  if (sub < 32) {   // self term g[i] (counted once after reduction)
    uint4 pv = *(const uint4*)(gpk + pidx(i, c));
    acc.x = unpacksum(pv.x); acc.y = unpacksum(pv.y);
    acc.z = unpacksum(pv.z); acc.w = unpacksum(pv.w);
  }
  int j = sub >> 5;
  for (; j + 2 < m; j += 4) {   // two loads in flight per thread
    int s0 = eidx[start + j], s1 = eidx[start + j + 2];
    uint4 p0 = *(const uint4*)(gpk + pidx(s0, c));
    uint4 p1 = *(const uint4*)(gpk + pidx(s1, c));
    acc.x += unpacksum(p0.x) + unpacksum(p1.x);
    acc.y += unpacksum(p0.y) + unpacksum(p1.y);
    acc.z += unpacksum(p0.z) + unpacksum(p1.z);
    acc.w += unpacksum(p0.w) + unpacksum(p1.w);
  }
  if (j < m) {
    int s = eidx[start + j];
    uint4 pv = *(const uint4*)(gpk + pidx(s, c));
    acc.x += unpacksum(pv.x); acc.y += unpacksum(pv.y);
    acc.z += unpacksum(pv.z); acc.w += unpacksum(pv.w);
  }
  acc.x += __shfl_xor(acc.x, 32);
  acc.y += __shfl_xor(acc.y, 32);
  acc.z += __shfl_xor(acc.z, 32);
  acc.w += __shfl_xor(acc.w, 32);
  if (sub < 32) {
    float ri = rnorm[i];
    float4 bv = *(const float4*)(bias + c);
    float4 o;
    o.x = fmaf(ri, acc.x, bv.x);
    o.y = fmaf(ri, acc.y, bv.y);
    o.z = fmaf(ri, acc.z, bv.z);
    o.w = fmaf(ri, acc.w, bv.w);
    *(float4*)(out + (size_t)i * DIM + c) = o;
  }
}

// =================== MFMA split-bf16 GEMM, packed swizzled A, LDS-staged W ===================
// SCALE: multiply output row r by rnorm[r] before packing (stage B writes g = rnorm.*h).
template<int PRE, int BIAS, int RELU, int OSPLIT, int SCALE>
__global__ __launch_bounds__(512) void gemm_mfma(
    const u32* __restrict__ Apk,
    const u16* __restrict__ Wgh, const u16* __restrict__ Wgl,
    const float* __restrict__ bias, const float* pre,
    const float* __restrict__ rnorm,
    float* outf, u32* opk, int nrows)
{
  __shared__ u16 Wh[DIM * WLD];   // 34.8 KB
  __shared__ u16 Wl[DIM * WLD];   // 34.8 KB
  const int tid = threadIdx.x;
  const int wave = tid >> 6, lane = tid & 63;
  const int lr = lane & 15, quad = lane >> 4;
  const int rowbase = blockIdx.x * 128 + wave * 16;   // 8 waves x 16 rows

  int arow = rowbase + lr;
  if (arow >= nrows) arow = nrows - 1;
  uint4 pa[4][2];
#pragma unroll
  for (int kk = 0; kk < 4; ++kk) {
    size_t o = pidx(arow, kk * 32 + quad * 8);
    pa[kk][0] = *(const uint4*)(Apk + o);
    pa[kk][1] = *(const uint4*)(Apk + o + 4);
  }

  for (int i = tid; i < DIM * DIM / 8; i += 512) {
    int cc = i >> 4, k8 = (i & 15) << 3;
    *(uint4*)&Wh[cc * WLD + k8] = ((const uint4*)Wgh)[i];
    *(uint4*)&Wl[cc * WLD + k8] = ((const uint4*)Wgl)[i];
  }
  __syncthreads();

  v8s afh[4], afl[4];
#pragma unroll
  for (int kk = 0; kk < 4; ++kk) {
    u32 u[8] = {pa[kk][0].x, pa[kk][0].y, pa[kk][0].z, pa[kk][0].w,
                pa[kk][1].x, pa[kk][1].y, pa[kk][1].z, pa[kk][1].w};
#pragma unroll
    for (int j = 0; j < 8; ++j) {
      afh[kk][j] = (short)(u[j] & 0xffffu);
      afl[kk][j] = (short)(u[j] >> 16);
    }
  }

  v4f acc[8];
#pragma unroll
  for (int ct = 0; ct < 8; ++ct) acc[ct] = (v4f){0.f, 0.f, 0.f, 0.f};

#pragma unroll
  for (int kk = 0; kk < 4; ++kk) {
#pragma unroll
    for (int ct = 0; ct < 8; ++ct) {
      const int wo = (ct * 16 + lr) * WLD + kk * 32 + quad * 8;
      v8s bh = *(const v8s*)&Wh[wo];
      v8s bl = *(const v8s*)&Wl[wo];
      acc[ct] = __builtin_amdgcn_mfma_f32_16x16x32_bf16(afh[kk], bh, acc[ct], 0, 0, 0);
      acc[ct] = __builtin_amdgcn_mfma_f32_16x16x32_bf16(afh[kk], bl, acc[ct], 0, 0, 0);
      acc[ct] = __builtin_amdgcn_mfma_f32_16x16x32_bf16(afl[kk], bh, acc[ct], 0, 0, 0);
    }
  }

  if (OSPLIT) {
    const size_t lanebase = ((size_t)(rowbase >> 4) << 11) + quad * 16 + lr;
#pragma unroll
    for (int rg = 0; rg < 4; ++rg) {
      int r = rowbase + quad * 4 + rg;
      if (r < nrows) {
        float sc = SCALE ? rnorm[r] : 1.f;
#pragma unroll
        for (int ct = 0; ct < 8; ++ct) {
          const int col = ct * 16 + lr;
          float v = acc[ct][rg] + (BIAS ? bias[col] : 0.f);
          if (PRE) v += pre[(size_t)r * DIM + col];
          if (RELU) v = fmaxf(v, 0.f);
          if (SCALE) v *= sc;
          opk[lanebase + (size_t)((rg << 3) + ct) * 64] = packsplit(v);
        }
      }
    }
  } else {
#pragma unroll
    for (int ct = 0; ct < 8; ++ct) {
      const int col = ct * 16 + lr;
      float bv = BIAS ? bias[col] : 0.f;
#pragma unroll
      for (int rg = 0; rg < 4; ++rg) {
        int r = rowbase + quad * 4 + rg;
        if (r < nrows) {
          size_t off = (size_t)r * DIM + col;
          float v = acc[ct][rg] + bv;
          if (PRE) v += pre[off];
          if (RELU) v = fmaxf(v, 0.f);
          outf[off] = v;
        }
      }
    }
  }
}

// =================== host ===================

extern "C" void kernel_launch(void* const* d_in, const int* in_sizes, int n_in,
                              void* d_out, int out_size, void* d_ws, size_t ws_size,
                              hipStream_t stream) {
  const float* emb = (const float*)d_in[0];
  const float* Wd  = (const float*)d_in[1];
  const float* bd  = (const float*)d_in[2];
  const float* Wg  = (const float*)d_in[3];
  const float* bg  = (const float*)d_in[4];
  const float* Wu  = (const float*)d_in[5];
  const float* bu  = (const float*)d_in[6];
  const int* d2u = (const int*)d_in[7];
  const int* sle = (const int*)d_in[8];
  const int* u2d = (const int*)d_in[9];
  const int E1 = in_sizes[7] / 2;   // 100000
  const int E2 = in_sizes[8] / 2;   // 600000
  const int E3 = in_sizes[9] / 2;   // 100000
  const int Etot = E1 + E2 + E3;
  const int N  = NNODES;
  const size_t nd = (size_t)N * DIM;

  u32* Apk  = (u32*)d_ws;          // packed swizzled plane [nd u32] (51.2 MB)
  int* cnt  = (int*)(Apk + nd);    // [3N]
  int* fill = cnt + 3 * N;         // [3N]
  int* rs   = fill + 3 * N;        // [3N]
  int* eidx = rs + 3 * N;          // [Etot]
  float* rnorm = (float*)(eidx + Etot);
  int* bsum = (int*)(rnorm + N);
  u16* Whi = (u16*)(bsum + 1024);
  u16* Wlo = Whi + 3 * DIM * DIM;
  float* bufB = (float*)d_out;

  const int gemm_blocks = (N + 127) / 128;        // 782
  const int nscan = (3 * N + 1023) / 1024;        // 293
  const int ngather = (N * 32 + 255) / 256;       // 12500 (32 t/node)
  const int ngcn = (N * 64 + 255) / 256;          // 25000 (64 t/node)

  // ---- prep: W planes + unified CSR ----
  (void)hipMemsetAsync(cnt, 0, (size_t)6 * N * sizeof(int), stream);
  make_w_planes<<<(3 * DIM * DIM + 255) / 256, 256, 0, stream>>>(Wd, Wg, Wu, Whi, Wlo);
  count_all<<<(Etot + 255) / 256, 256, 0, stream>>>(d2u, sle, u2d, E1, E2, E3, cnt);
  make_rnorm<<<(N + 255) / 256, 256, 0, stream>>>(cnt + N, rnorm, N);
  scan_blocks<<<nscan, 256, 0, stream>>>(cnt, rs, bsum, 3 * N);
  scan_top<<<1, 256, 0, stream>>>(bsum, nscan);
  scan_add<<<nscan, 256, 0, stream>>>(rs, bsum, 3 * N);
  fill_all<<<(Etot + 255) / 256, 256, 0, stream>>>(d2u, sle, u2d, E1, E2, E3, rs, fill, eidx);

  // ---- stage A: agg1 = mean(emb) -> packed ; x1 = relu(emb + agg1@Wd + bd) -> packed (in-place) ----
  gather_mean_pack<<<ngather, 256, 0, stream>>>(emb, rs, cnt, eidx, Apk, N);
  gemm_mfma<1, 1, 1, 1, 0><<<gemm_blocks, 512, 0, stream>>>(Apk, Whi, Wlo, bd, emb,
                                                            nullptr, nullptr, Apk, N);

  // ---- stage B: g = rnorm.*(x1@Wg) -> packed (in-place) ; x2 = gcn(g) -> d_out ----
  gemm_mfma<0, 0, 0, 1, 1><<<gemm_blocks, 512, 0, stream>>>(Apk, Whi + DIM * DIM,
                                                            Wlo + DIM * DIM, nullptr, nullptr,
                                                            rnorm, nullptr, Apk, N);
  gather_gcn<<<ngcn, 256, 0, stream>>>(Apk, rs + N, cnt + N, eidx, rnorm, bg, bufB, N);

  // ---- stage C: agg2 = mean(x2) -> packed ; out = relu(x2 + agg2@Wu + bu) -> f32 d_out ----
  gather_mean_pack<<<ngather, 256, 0, stream>>>(bufB, rs + 2 * N, cnt + 2 * N, eidx, Apk, N);
  gemm_mfma<1, 1, 1, 0, 0><<<gemm_blocks, 512, 0, stream>>>(Apk, Whi + 2 * DIM * DIM,
                                                            Wlo + 2 * DIM * DIM, bu, bufB,
                                                            nullptr, bufB, nullptr, N);
}

// Round 13
// 383.480 us; speedup vs baseline: 1.1813x; 1.1519x over previous
//
#include <hip/hip_runtime.h>
#include <cstdint>
#include <cstddef>

#define NNODES 100000
#define DIM 128
#define WLD 136   // LDS stride (u16) for W planes
#define TLD 144   // LDS stride (u16) for epilogue transpose: conflict-free u16 tiles

typedef unsigned short u16;
typedef uint32_t u32;
typedef __attribute__((ext_vector_type(8))) short v8s;
typedef __attribute__((ext_vector_type(4))) float v4f;

__device__ __forceinline__ float bf2f(u32 u) {
  union { u32 i; float f; } x; x.i = u << 16; return x.f;
}
__device__ __forceinline__ u16 f2bf(float f) {
  union { float f; u32 i; } x; x.f = f;
  u32 r = x.i + 0x7fffu + ((x.i >> 16) & 1u);  // RNE
  return (u16)(r >> 16);
}
__device__ __forceinline__ u32 packsplit(float f) {
  u16 h = f2bf(f);
  float r = f - bf2f(h);
  u16 l = f2bf(r);
  return (u32)h | ((u32)l << 16);
}
__device__ __forceinline__ float unpacksum(u32 p) {
  return bf2f(p & 0xffffu) + bf2f(p >> 16);
}

// swizzled packed-plane index (u32 planes): wave-store of one (rg,ct) slab = 256 B contig
__device__ __forceinline__ size_t pidx(int row, int col) {
  return ((size_t)(row >> 4) << 11) +
         (size_t)(((((row & 3) << 3) + (col >> 4)) << 6) +
                  (((row >> 2) & 3) << 4) + (col & 15));
}

// =================== unified CSR build (3 lists concatenated) ===================

__global__ void count_all(const int* __restrict__ d2u, const int* __restrict__ sle,
                          const int* __restrict__ u2d, int E1, int E2, int E3,
                          int* __restrict__ cnt) {
  int e = blockIdx.x * 256 + threadIdx.x;
  int idx;
  if (e < E1)            idx = d2u[E1 + e];
  else if (e < E1 + E2)  idx = NNODES + sle[E2 + (e - E1)];
  else if (e < E1 + E2 + E3) idx = 2 * NNODES + u2d[E3 + (e - E1 - E2)];
  else return;
  atomicAdd(&cnt[idx], 1);
}

__global__ void fill_all(const int* __restrict__ d2u, const int* __restrict__ sle,
                         const int* __restrict__ u2d, int E1, int E2, int E3,
                         const int* __restrict__ rs, int* __restrict__ fill,
                         int* __restrict__ eidx) {
  int e = blockIdx.x * 256 + threadIdx.x;
  int idx, src;
  if (e < E1)            { idx = d2u[E1 + e];                src = d2u[e]; }
  else if (e < E1 + E2)  { int q = e - E1; idx = NNODES + sle[E2 + q];     src = sle[q]; }
  else if (e < E1 + E2 + E3) { int q = e - E1 - E2; idx = 2 * NNODES + u2d[E3 + q]; src = u2d[q]; }
  else return;
  int p = rs[idx] + atomicAdd(&fill[idx], 1);
  eidx[p] = src;
}

__global__ void scan_blocks(const int* __restrict__ in, int* __restrict__ out,
                            int* __restrict__ bsum, int n) {
  __shared__ int wsum[4];
  const int tid = threadIdx.x;
  const int base = blockIdx.x * 1024 + tid * 4;
  int v0 = 0, v1 = 0, v2 = 0, v3 = 0;
  if (base + 0 < n) v0 = in[base + 0];
  if (base + 1 < n) v1 = in[base + 1];
  if (base + 2 < n) v2 = in[base + 2];
  if (base + 3 < n) v3 = in[base + 3];
  const int tsum = v0 + v1 + v2 + v3;
  const int lane = tid & 63, wid = tid >> 6;
  int x = tsum;
  for (int off = 1; off < 64; off <<= 1) {
    int y = __shfl_up(x, off, 64);
    if (lane >= off) x += y;
  }
  if (lane == 63) wsum[wid] = x;
  __syncthreads();
  int woff = 0;
  for (int w = 0; w < wid; ++w) woff += wsum[w];
  const int excl = woff + x - tsum;
  if (base + 0 < n) out[base + 0] = excl;
  if (base + 1 < n) out[base + 1] = excl + v0;
  if (base + 2 < n) out[base + 2] = excl + v0 + v1;
  if (base + 3 < n) out[base + 3] = excl + v0 + v1 + v2;
  if (tid == 255) bsum[blockIdx.x] = woff + x;
}

__global__ void scan_top(int* __restrict__ bsum, int nb) {
  __shared__ int tmp[1024];
  const int tid = threadIdx.x;
  for (int i = tid; i < 1024; i += 256) tmp[i] = (i < nb) ? bsum[i] : 0;
  __syncthreads();
  for (int off = 1; off < 1024; off <<= 1) {
    int vals[4];
#pragma unroll
    for (int j = 0; j < 4; ++j) { int i = tid + j * 256; vals[j] = (i >= off) ? tmp[i - off] : 0; }
    __syncthreads();
#pragma unroll
    for (int j = 0; j < 4; ++j) { int i = tid + j * 256; tmp[i] += vals[j]; }
    __syncthreads();
  }
  for (int i = tid; i < nb; i += 256) {
    int orig = bsum[i];
    bsum[i] = tmp[i] - orig;   // exclusive
  }
}

__global__ void scan_add(int* __restrict__ out, const int* __restrict__ bsum, int n) {
  const int b = blockIdx.x;
  const int off = bsum[b];
  const int base = b * 1024 + threadIdx.x * 4;
#pragma unroll
  for (int j = 0; j < 4; ++j)
    if (base + j < n) out[base + j] += off;
}

__global__ void make_rnorm(const int* __restrict__ cntB, float* __restrict__ rnorm, int n) {
  int i = blockIdx.x * 256 + threadIdx.x;
  if (i < n) rnorm[i] = rsqrtf((float)cntB[i] + 1.0f);
}

__global__ void make_w_planes(const float* __restrict__ W0, const float* __restrict__ W1,
                              const float* __restrict__ W2,
                              u16* __restrict__ Whi, u16* __restrict__ Wlo) {
  int i = blockIdx.x * 256 + threadIdx.x;
  if (i >= 3 * DIM * DIM) return;
  int m = i / (DIM * DIM);
  int idx = i - m * DIM * DIM;
  int k = idx >> 7, c = idx & 127;
  const float* W = (m == 0) ? W0 : ((m == 1) ? W1 : W2);
  u32 p = packsplit(W[idx]);
  int o = m * DIM * DIM + c * DIM + k;
  Whi[o] = (u16)(p & 0xffffu);
  Wlo[o] = (u16)(p >> 16);
}

// =================== gathers ===================

// agg[i] = mean of x[src] rows; write packed swizzled plane (32 t/node)
__global__ void gather_mean_pack(const float* __restrict__ x, const int* __restrict__ rs,
                                 const int* __restrict__ cnt, const int* __restrict__ eidx,
                                 u32* __restrict__ opk, int n) {
  int gid = blockIdx.x * 256 + threadIdx.x;
  int i = gid >> 5;
  if (i >= n) return;
  int c = (gid & 31) << 2;
  int start = rs[i], m = cnt[i];
  float4 acc = {0.f, 0.f, 0.f, 0.f};
  int j = 0;
  for (; j + 1 < m; j += 2) {
    int s0 = eidx[start + j], s1 = eidx[start + j + 1];
    float4 v0 = *(const float4*)(x + (size_t)s0 * DIM + c);
    float4 v1 = *(const float4*)(x + (size_t)s1 * DIM + c);
    acc.x += v0.x + v1.x; acc.y += v0.y + v1.y;
    acc.z += v0.z + v1.z; acc.w += v0.w + v1.w;
  }
  if (j < m) {
    int s = eidx[start + j];
    float4 v = *(const float4*)(x + (size_t)s * DIM + c);
    acc.x += v.x; acc.y += v.y; acc.z += v.z; acc.w += v.w;
  }
  float inv = 1.0f / fmaxf((float)m, 1.0f);
  uint4 pk;
  pk.x = packsplit(acc.x * inv);
  pk.y = packsplit(acc.y * inv);
  pk.z = packsplit(acc.z * inv);
  pk.w = packsplit(acc.w * inv);
  *(uint4*)(opk + pidx(i, c)) = pk;
}

// x2[i] = ri*(sum_e g[s] + g[i]) + bg, g = rnorm.*h stored as ROW-MAJOR bf16
// (halves the 307 MB random read floor). 64 t/node, 2-way edge-parallel,
// unroll-2, shfl_xor(32) reduce.
__global__ void gather_gcn(const u16* __restrict__ g,
                           const int* __restrict__ rs, const int* __restrict__ cnt,
                           const int* __restrict__ eidx, const float* __restrict__ rnorm,
                           const float* __restrict__ bias, float* __restrict__ out, int n) {
  int gid = blockIdx.x * 256 + threadIdx.x;
  int i = gid >> 6;
  if (i >= n) return;
  int sub = gid & 63;
  int c = (sub & 31) << 2;
  int start = rs[i], m = cnt[i];
  float4 acc = {0.f, 0.f, 0.f, 0.f};
  if (sub < 32) {   // self term g[i]
    ushort4 pv = *(const ushort4*)(g + ((size_t)i << 7) + c);
    acc.x = bf2f(pv.x); acc.y = bf2f(pv.y);
    acc.z = bf2f(pv.z); acc.w = bf2f(pv.w);
  }
  int j = sub >> 5;
  for (; j + 2 < m; j += 4) {   // two row loads in flight per thread
    int s0 = eidx[start + j], s1 = eidx[start + j + 2];
    ushort4 p0 = *(const ushort4*)(g + ((size_t)s0 << 7) + c);
    ushort4 p1 = *(const ushort4*)(g + ((size_t)s1 << 7) + c);
    acc.x += bf2f(p0.x) + bf2f(p1.x);
    acc.y += bf2f(p0.y) + bf2f(p1.y);
    acc.z += bf2f(p0.z) + bf2f(p1.z);
    acc.w += bf2f(p0.w) + bf2f(p1.w);
  }
  if (j < m) {
    int s = eidx[start + j];
    ushort4 pv = *(const ushort4*)(g + ((size_t)s << 7) + c);
    acc.x += bf2f(pv.x); acc.y += bf2f(pv.y);
    acc.z += bf2f(pv.z); acc.w += bf2f(pv.w);
  }
  acc.x += __shfl_xor(acc.x, 32);
  acc.y += __shfl_xor(acc.y, 32);
  acc.z += __shfl_xor(acc.z, 32);
  acc.w += __shfl_xor(acc.w, 32);
  if (sub < 32) {
    float ri = rnorm[i];
    float4 bv = *(const float4*)(bias + c);
    float4 o;
    o.x = fmaf(ri, acc.x, bv.x);
    o.y = fmaf(ri, acc.y, bv.y);
    o.z = fmaf(ri, acc.z, bv.z);
    o.w = fmaf(ri, acc.w, bv.w);
    *(float4*)(out + (size_t)i * DIM + c) = o;
  }
}

// =================== MFMA split-bf16 GEMM, packed swizzled A, LDS-staged W ===================
// OUT: 0 = f32 row-major; 1 = packed u32 swizzled plane; 2 = bf16 row-major via
// LDS transpose (reuse W LDS post-barrier; pad TLD=144 -> conflict-free, then
// block-coalesced uint4 row stores). SCALE: multiply row r by rnorm[r].
template<int PRE, int BIAS, int RELU, int OUT, int SCALE>
__global__ __launch_bounds__(512) void gemm_mfma(
    const u32* __restrict__ Apk,
    const u16* __restrict__ Wgh, const u16* __restrict__ Wgl,
    const float* __restrict__ bias, const float* pre,
    const float* __restrict__ rnorm,
    float* outf, u32* opk, u16* obf, int nrows)
{
  __shared__ u16 S[2 * DIM * WLD];   // 69.6 KB: W hi | W lo ; reused as transpose buf
  u16* Wh = S;
  u16* Wl = S + DIM * WLD;
  const int tid = threadIdx.x;
  const int wave = tid >> 6, lane = tid & 63;
  const int lr = lane & 15, quad = lane >> 4;
  const int rowbase = blockIdx.x * 128 + wave * 16;   // 8 waves x 16 rows

  int arow = rowbase + lr;
  if (arow >= nrows) arow = nrows - 1;
  uint4 pa[4][2];
#pragma unroll
  for (int kk = 0; kk < 4; ++kk) {
    size_t o = pidx(arow, kk * 32 + quad * 8);
    pa[kk][0] = *(const uint4*)(Apk + o);
    pa[kk][1] = *(const uint4*)(Apk + o + 4);
  }

  for (int i = tid; i < DIM * DIM / 8; i += 512) {
    int cc = i >> 4, k8 = (i & 15) << 3;
    *(uint4*)&Wh[cc * WLD + k8] = ((const uint4*)Wgh)[i];
    *(uint4*)&Wl[cc * WLD + k8] = ((const uint4*)Wgl)[i];
  }
  __syncthreads();

  v8s afh[4], afl[4];
#pragma unroll
  for (int kk = 0; kk < 4; ++kk) {
    u32 u[8] = {pa[kk][0].x, pa[kk][0].y, pa[kk][0].z, pa[kk][0].w,
                pa[kk][1].x, pa[kk][1].y, pa[kk][1].z, pa[kk][1].w};
#pragma unroll
    for (int j = 0; j < 8; ++j) {
      afh[kk][j] = (short)(u[j] & 0xffffu);
      afl[kk][j] = (short)(u[j] >> 16);
    }
  }

  v4f acc[8];
#pragma unroll
  for (int ct = 0; ct < 8; ++ct) acc[ct] = (v4f){0.f, 0.f, 0.f, 0.f};

#pragma unroll
  for (int kk = 0; kk < 4; ++kk) {
#pragma unroll
    for (int ct = 0; ct < 8; ++ct) {
      const int wo = (ct * 16 + lr) * WLD + kk * 32 + quad * 8;
      v8s bh = *(const v8s*)&Wh[wo];
      v8s bl = *(const v8s*)&Wl[wo];
      acc[ct] = __builtin_amdgcn_mfma_f32_16x16x32_bf16(afh[kk], bh, acc[ct], 0, 0, 0);
      acc[ct] = __builtin_amdgcn_mfma_f32_16x16x32_bf16(afh[kk], bl, acc[ct], 0, 0, 0);
      acc[ct] = __builtin_amdgcn_mfma_f32_16x16x32_bf16(afl[kk], bh, acc[ct], 0, 0, 0);
    }
  }

  if (OUT == 1) {
    const size_t lanebase = ((size_t)(rowbase >> 4) << 11) + quad * 16 + lr;
#pragma unroll
    for (int rg = 0; rg < 4; ++rg) {
      int r = rowbase + quad * 4 + rg;
      if (r < nrows) {
        float sc = SCALE ? rnorm[r] : 1.f;
#pragma unroll
        for (int ct = 0; ct < 8; ++ct) {
          const int col = ct * 16 + lr;
          float v = acc[ct][rg] + (BIAS ? bias[col] : 0.f);
          if (PRE) v += pre[(size_t)r * DIM + col];
          if (RELU) v = fmaxf(v, 0.f);
          if (SCALE) v *= sc;
          opk[lanebase + (size_t)((rg << 3) + ct) * 64] = packsplit(v);
        }
      }
    }
  } else if (OUT == 2) {
    __syncthreads();   // all waves finished with W LDS; reuse S as transpose buf
    const int lrow0 = wave * 16 + quad * 4;
#pragma unroll
    for (int rg = 0; rg < 4; ++rg) {
      int lrow = lrow0 + rg;
      int r = blockIdx.x * 128 + lrow;
      float sc = SCALE ? rnorm[(r < nrows) ? r : (nrows - 1)] : 1.f;
#pragma unroll
      for (int ct = 0; ct < 8; ++ct) {
        float v = acc[ct][rg] + (BIAS ? bias[ct * 16 + lr] : 0.f);
        if (RELU) v = fmaxf(v, 0.f);
        if (SCALE) v *= sc;
        S[lrow * TLD + ct * 16 + lr] = f2bf(v);
      }
    }
    __syncthreads();
    const int rowstart = blockIdx.x * 128;
    for (int idx = tid; idx < 128 * 16; idx += 512) {   // 2048 uint4 row stores
      int lrow = idx >> 4, c8 = (idx & 15) << 3;
      int r = rowstart + lrow;
      if (r < nrows)
        *(uint4*)(obf + ((size_t)r << 7) + c8) = *(const uint4*)&S[lrow * TLD + c8];
    }
  } else {
#pragma unroll
    for (int ct = 0; ct < 8; ++ct) {
      const int col = ct * 16 + lr;
      float bv = BIAS ? bias[col] : 0.f;
#pragma unroll
      for (int rg = 0; rg < 4; ++rg) {
        int r = rowbase + quad * 4 + rg;
        if (r < nrows) {
          size_t off = (size_t)r * DIM + col;
          float v = acc[ct][rg] + bv;
          if (PRE) v += pre[off];
          if (RELU) v = fmaxf(v, 0.f);
          outf[off] = v;
        }
      }
    }
  }
}

// =================== host ===================

extern "C" void kernel_launch(void* const* d_in, const int* in_sizes, int n_in,
                              void* d_out, int out_size, void* d_ws, size_t ws_size,
                              hipStream_t stream) {
  const float* emb = (const float*)d_in[0];
  const float* Wd  = (const float*)d_in[1];
  const float* bd  = (const float*)d_in[2];
  const float* Wg  = (const float*)d_in[3];
  const float* bg  = (const float*)d_in[4];
  const float* Wu  = (const float*)d_in[5];
  const float* bu  = (const float*)d_in[6];
  const int* d2u = (const int*)d_in[7];
  const int* sle = (const int*)d_in[8];
  const int* u2d = (const int*)d_in[9];
  const int E1 = in_sizes[7] / 2;   // 100000
  const int E2 = in_sizes[8] / 2;   // 600000
  const int E3 = in_sizes[9] / 2;   // 100000
  const int Etot = E1 + E2 + E3;
  const int N  = NNODES;
  const size_t nd = (size_t)N * DIM;

  u32* Apk  = (u32*)d_ws;          // packed swizzled plane [nd u32] (51.2 MB)
  u16* Gbf  = (u16*)(Apk + nd);    // row-major bf16 g plane [nd u16] (25.6 MB)
  int* cnt  = (int*)(Gbf + nd);    // [3N]
  int* fill = cnt + 3 * N;         // [3N]
  int* rs   = fill + 3 * N;        // [3N]
  int* eidx = rs + 3 * N;          // [Etot]
  float* rnorm = (float*)(eidx + Etot);
  int* bsum = (int*)(rnorm + N);
  u16* Whi = (u16*)(bsum + 1024);
  u16* Wlo = Whi + 3 * DIM * DIM;
  float* bufB = (float*)d_out;

  const int gemm_blocks = (N + 127) / 128;        // 782
  const int nscan = (3 * N + 1023) / 1024;        // 293
  const int ngather = (N * 32 + 255) / 256;       // 12500 (32 t/node)
  const int ngcn = (N * 64 + 255) / 256;          // 25000 (64 t/node)

  // ---- prep: W planes + unified CSR ----
  (void)hipMemsetAsync(cnt, 0, (size_t)6 * N * sizeof(int), stream);
  make_w_planes<<<(3 * DIM * DIM + 255) / 256, 256, 0, stream>>>(Wd, Wg, Wu, Whi, Wlo);
  count_all<<<(Etot + 255) / 256, 256, 0, stream>>>(d2u, sle, u2d, E1, E2, E3, cnt);
  make_rnorm<<<(N + 255) / 256, 256, 0, stream>>>(cnt + N, rnorm, N);
  scan_blocks<<<nscan, 256, 0, stream>>>(cnt, rs, bsum, 3 * N);
  scan_top<<<1, 256, 0, stream>>>(bsum, nscan);
  scan_add<<<nscan, 256, 0, stream>>>(rs, bsum, 3 * N);
  fill_all<<<(Etot + 255) / 256, 256, 0, stream>>>(d2u, sle, u2d, E1, E2, E3, rs, fill, eidx);

  // ---- stage A: agg1 = mean(emb) -> packed ; x1 = relu(emb + agg1@Wd + bd) -> packed (in-place) ----
  gather_mean_pack<<<ngather, 256, 0, stream>>>(emb, rs, cnt, eidx, Apk, N);
  gemm_mfma<1, 1, 1, 1, 0><<<gemm_blocks, 512, 0, stream>>>(Apk, Whi, Wlo, bd, emb,
                                                            nullptr, nullptr, Apk, nullptr, N);

  // ---- stage B: g = rnorm.*(x1@Wg) -> bf16 row-major ; x2 = gcn(g) -> d_out (f32) ----
  gemm_mfma<0, 0, 0, 2, 1><<<gemm_blocks, 512, 0, stream>>>(Apk, Whi + DIM * DIM,
                                                            Wlo + DIM * DIM, nullptr, nullptr,
                                                            rnorm, nullptr, nullptr, Gbf, N);
  gather_gcn<<<ngcn, 256, 0, stream>>>(Gbf, rs + N, cnt + N, eidx, rnorm, bg, bufB, N);

  // ---- stage C: agg2 = mean(x2) -> packed ; out = relu(x2 + agg2@Wu + bu) -> f32 d_out ----
  gather_mean_pack<<<ngather, 256, 0, stream>>>(bufB, rs + 2 * N, cnt + 2 * N, eidx, Apk, N);
  gemm_mfma<1, 1, 1, 0, 0><<<gemm_blocks, 512, 0, stream>>>(Apk, Whi + 2 * DIM * DIM,
                                                            Wlo + 2 * DIM * DIM, bu, bufB,
                                                            nullptr, bufB, nullptr, nullptr, N);
}